// Round 3
// baseline (262.060 us; speedup 1.0000x reference)
//
#include <hip/hip_runtime.h>
#include <hip/hip_bf16.h>

// LinearAttention: B=16, H=W=64 (N=4096 spatial), C=256.
// y[n,co] = sum_d q[n,d] * Wc[b][d,co] + b_out[co]
//   Wc = diag(1/S) * (E^T V) * W_out,  E = exp(k), S[d] = sum_n E[n,d]
// Pipeline: k_wt (transpose weights to bf16, zero S) -> k_qkv (GEMM + exp + S)
//           -> k_ctx (split-K E^T V partials) -> k_wc (reduce+scale+GEMM W_out)
//           -> k_out (Q @ Wc + b_out)

typedef __bf16 bf16;
typedef __bf16 bf16x4 __attribute__((ext_vector_type(4)));
typedef __bf16 bf16x8 __attribute__((ext_vector_type(8)));
typedef float  f32x4  __attribute__((ext_vector_type(4)));

#define LDP 72  // LDS row stride in bf16 elems: 144B = 9*16B -> aligned, ~conflict-free

__device__ __forceinline__ bf16 tob(float f) { return (bf16)f; }

// One 128x128 output tile, 4 waves in 2x2, each wave 64x64 = 4x4 fragments of
// 16x16, K-step of 64 (two 16x16x32 MFMAs deep).
__device__ __forceinline__ void compute_tile(const bf16* As, const bf16* Bs,
                                             f32x4 acc[4][4], int wr, int wc,
                                             int lr, int g) {
#pragma unroll
  for (int ks = 0; ks < 2; ++ks) {
    bf16x8 a[4], b[4];
#pragma unroll
    for (int m = 0; m < 4; ++m)
      a[m] = *reinterpret_cast<const bf16x8*>(&As[(wr * 64 + m * 16 + lr) * LDP + ks * 32 + g * 8]);
#pragma unroll
    for (int n = 0; n < 4; ++n)
      b[n] = *reinterpret_cast<const bf16x8*>(&Bs[(wc * 64 + n * 16 + lr) * LDP + ks * 32 + g * 8]);
#pragma unroll
    for (int m = 0; m < 4; ++m)
#pragma unroll
      for (int n = 0; n < 4; ++n)
        acc[m][n] = __builtin_amdgcn_mfma_f32_16x16x32_bf16(a[m], b[n], acc[m][n], 0, 0, 0);
  }
}

// --- weight prep: WqT[n][k]=Wq[k][n] bf16, WoT[co][e]=Wo[e][co] bf16, S=0 ---
__global__ __launch_bounds__(256) void k_wt(const float* __restrict__ Wq,
                                            const float* __restrict__ Wo,
                                            bf16* __restrict__ WqT,
                                            bf16* __restrict__ WoT,
                                            float* __restrict__ S) {
  int idx = blockIdx.x * 256 + threadIdx.x;  // grid 1024*256 = 262144 exact
  if (idx < 196608) {
    int n = idx >> 8, k = idx & 255;
    WqT[idx] = tob(Wq[(size_t)k * 768 + n]);
  } else {
    int i2 = idx - 196608;
    int co = i2 >> 8, e = i2 & 255;
    WoT[i2] = tob(Wo[(size_t)e * 256 + co]);
  }
  if (idx < 4096) S[idx] = 0.0f;
}

// --- QKV GEMM: x[65536,256] fp32 @ WqT -> Q[n,c], Et[b,c,n]=exp(k), Vt[b,c,n]
__global__ __launch_bounds__(256) void k_qkv(const float* __restrict__ x,
                                             const bf16* __restrict__ WqT,
                                             bf16* __restrict__ Q,
                                             bf16* __restrict__ Et,
                                             bf16* __restrict__ Vt,
                                             float* __restrict__ S) {
  __shared__ __align__(16) bf16 As[128 * LDP];
  __shared__ __align__(16) bf16 Bs[128 * LDP];
  int bx = blockIdx.x;
  int rb = bx / 6, cb = bx % 6;
  int tid = threadIdx.x;
  int lane = tid & 63, w = tid >> 6;
  int wr = w >> 1, wc = w & 1;
  int g = lane >> 4, lr = lane & 15;
  const int rowbase = rb * 128, colbase = cb * 128;

  f32x4 acc[4][4];
#pragma unroll
  for (int m = 0; m < 4; ++m)
#pragma unroll
    for (int n = 0; n < 4; ++n) acc[m][n] = (f32x4)0.0f;

  for (int kt = 0; kt < 4; ++kt) {
    int k0 = kt * 64;
    __syncthreads();
    // A: x fp32 -> bf16, 128x64
#pragma unroll
    for (int r = 0; r < 8; ++r) {
      int idx = r * 1024 + tid * 4;
      int row = idx >> 6, col = idx & 63;
      float4 v = *reinterpret_cast<const float4*>(x + (size_t)(rowbase + row) * 256 + k0 + col);
      bf16x4 p;
      p[0] = tob(v.x); p[1] = tob(v.y); p[2] = tob(v.z); p[3] = tob(v.w);
      *reinterpret_cast<bf16x4*>(&As[row * LDP + col]) = p;
    }
    // B: WqT rows = output cols, K-contig
#pragma unroll
    for (int r = 0; r < 4; ++r) {
      int idx = r * 2048 + tid * 8;
      int row = idx >> 6, col = idx & 63;
      bf16x8 v = *reinterpret_cast<const bf16x8*>(WqT + (size_t)(colbase + row) * 256 + k0 + col);
      *reinterpret_cast<bf16x8*>(&Bs[row * LDP + col]) = v;
    }
    __syncthreads();
    compute_tile(As, Bs, acc, wr, wc, lr, g);
  }

  int grow = rowbase + wr * 64;
  int gcol = colbase + wc * 64;
  int sec = gcol >> 8;       // 0=Q 1=K 2=V (64-wide wave tile never straddles)
  int coff = gcol & 255;
  int b = grow >> 12;
  int nsp = grow & 4095;

  if (sec == 0) {
#pragma unroll
    for (int m = 0; m < 4; ++m)
#pragma unroll
      for (int n = 0; n < 4; ++n) {
        int col = coff + n * 16 + lr;
#pragma unroll
        for (int t = 0; t < 4; ++t) {
          int row = grow + m * 16 + g * 4 + t;
          Q[(size_t)row * 256 + col] = tob(acc[m][n][t]);
        }
      }
  } else {
    bf16* dst = (sec == 1) ? Et : Vt;
    float cs0 = 0.f, cs1 = 0.f, cs2 = 0.f, cs3 = 0.f;
#pragma unroll
    for (int m = 0; m < 4; ++m)
#pragma unroll
      for (int n = 0; n < 4; ++n) {
        int col = coff + n * 16 + lr;
        int nn0 = nsp + m * 16 + g * 4;
        bf16x4 p;
#pragma unroll
        for (int t = 0; t < 4; ++t) {
          float v = acc[m][n][t];
          if (sec == 1) {
            v = expf(v);
            if (n == 0) cs0 += v; else if (n == 1) cs1 += v;
            else if (n == 2) cs2 += v; else cs3 += v;
          }
          p[t] = tob(v);
        }
        *reinterpret_cast<bf16x4*>(&dst[((size_t)(b * 256 + col) << 12) + nn0]) = p;
      }
    if (sec == 1) {
      cs0 += __shfl_xor(cs0, 16); cs0 += __shfl_xor(cs0, 32);
      cs1 += __shfl_xor(cs1, 16); cs1 += __shfl_xor(cs1, 32);
      cs2 += __shfl_xor(cs2, 16); cs2 += __shfl_xor(cs2, 32);
      cs3 += __shfl_xor(cs3, 16); cs3 += __shfl_xor(cs3, 32);
      float v = (g == 0) ? cs0 : (g == 1) ? cs1 : (g == 2) ? cs2 : cs3;
      atomicAdd(&S[b * 256 + coff + g * 16 + lr], v);
    }
  }
}

// --- context partials: part[b][s][d][e] = sum_{n in slice s} Et[d,n]*Vt[e,n]
__global__ __launch_bounds__(256) void k_ctx(const bf16* __restrict__ Et,
                                             const bf16* __restrict__ Vt,
                                             float* __restrict__ part) {
  __shared__ __align__(16) bf16 As[128 * LDP];
  __shared__ __align__(16) bf16 Bs[128 * LDP];
  int bx = blockIdx.x;
  int tile = bx & 3, dblk = tile >> 1, eblk = tile & 1;
  int s = (bx >> 2) & 3;
  int b = bx >> 4;
  int tid = threadIdx.x;
  int lane = tid & 63, w = tid >> 6;
  int wr = w >> 1, wc = w & 1;
  int g = lane >> 4, lr = lane & 15;

  const bf16* Ab = Et + ((size_t)(b * 256 + dblk * 128) << 12);
  const bf16* Bb = Vt + ((size_t)(b * 256 + eblk * 128) << 12);
  int n0 = s * 1024;

  f32x4 acc[4][4];
#pragma unroll
  for (int m = 0; m < 4; ++m)
#pragma unroll
    for (int n = 0; n < 4; ++n) acc[m][n] = (f32x4)0.0f;

  for (int kt = 0; kt < 16; ++kt) {
    int k0 = n0 + kt * 64;
    __syncthreads();
#pragma unroll
    for (int r = 0; r < 4; ++r) {
      int idx = r * 2048 + tid * 8;
      int row = idx >> 6, col = idx & 63;
      bf16x8 va = *reinterpret_cast<const bf16x8*>(Ab + (size_t)row * 4096 + k0 + col);
      *reinterpret_cast<bf16x8*>(&As[row * LDP + col]) = va;
      bf16x8 vb = *reinterpret_cast<const bf16x8*>(Bb + (size_t)row * 4096 + k0 + col);
      *reinterpret_cast<bf16x8*>(&Bs[row * LDP + col]) = vb;
    }
    __syncthreads();
    compute_tile(As, Bs, acc, wr, wc, lr, g);
  }

  float* p = part + (size_t)(b * 4 + s) * 65536;
  int dbase = dblk * 128 + wr * 64;
  int ebase = eblk * 128 + wc * 64;
#pragma unroll
  for (int m = 0; m < 4; ++m)
#pragma unroll
    for (int n = 0; n < 4; ++n)
#pragma unroll
      for (int t = 0; t < 4; ++t)
        p[(size_t)(dbase + m * 16 + g * 4 + t) * 256 + ebase + n * 16 + lr] = acc[m][n][t];
}

// --- Wc^T[b][co][d] = sum_e (sum_s part)/S[d] * Wo[e][co], bf16
__global__ __launch_bounds__(256) void k_wc(const float* __restrict__ part,
                                            const float* __restrict__ S,
                                            const bf16* __restrict__ WoT,
                                            bf16* __restrict__ WcT) {
  __shared__ __align__(16) bf16 As[128 * LDP];
  __shared__ __align__(16) bf16 Bs[128 * LDP];
  int bx = blockIdx.x;
  int b = bx >> 2, dblk = (bx >> 1) & 1, cblk = bx & 1;
  int tid = threadIdx.x;
  int lane = tid & 63, w = tid >> 6;
  int wr = w >> 1, wc = w & 1;
  int g = lane >> 4, lr = lane & 15;
  const float* p0 = part + (size_t)b * 4 * 65536;

  f32x4 acc[4][4];
#pragma unroll
  for (int m = 0; m < 4; ++m)
#pragma unroll
    for (int n = 0; n < 4; ++n) acc[m][n] = (f32x4)0.0f;

  for (int kt = 0; kt < 4; ++kt) {
    int k0 = kt * 64;
    __syncthreads();
    // A: context rows (d), cols (e), reduce 4 split-K partials, scale 1/S[d]
#pragma unroll
    for (int r = 0; r < 8; ++r) {
      int idx = r * 1024 + tid * 4;
      int row = idx >> 6, col = idx & 63;
      int d = dblk * 128 + row;
      size_t off = (size_t)d * 256 + k0 + col;
      float4 v0 = *reinterpret_cast<const float4*>(p0 + off);
      float4 v1 = *reinterpret_cast<const float4*>(p0 + 65536 + off);
      float4 v2 = *reinterpret_cast<const float4*>(p0 + 2 * 65536 + off);
      float4 v3 = *reinterpret_cast<const float4*>(p0 + 3 * 65536 + off);
      float rs = 1.0f / S[b * 256 + d];
      bf16x4 p;
      p[0] = tob((v0.x + v1.x + v2.x + v3.x) * rs);
      p[1] = tob((v0.y + v1.y + v2.y + v3.y) * rs);
      p[2] = tob((v0.z + v1.z + v2.z + v3.z) * rs);
      p[3] = tob((v0.w + v1.w + v2.w + v3.w) * rs);
      *reinterpret_cast<bf16x4*>(&As[row * LDP + col]) = p;
    }
    // B: WoT[co][e]
#pragma unroll
    for (int r = 0; r < 4; ++r) {
      int idx = r * 2048 + tid * 8;
      int row = idx >> 6, col = idx & 63;
      bf16x8 v = *reinterpret_cast<const bf16x8*>(WoT + (size_t)(cblk * 128 + row) * 256 + k0 + col);
      *reinterpret_cast<bf16x8*>(&Bs[row * LDP + col]) = v;
    }
    __syncthreads();
    compute_tile(As, Bs, acc, wr, wc, lr, g);
  }

  int dbase = dblk * 128 + wr * 64;
  int cbase = cblk * 128 + wc * 64;
#pragma unroll
  for (int m = 0; m < 4; ++m)
#pragma unroll
    for (int n = 0; n < 4; ++n) {
      int co = cbase + n * 16 + lr;
      int d0 = dbase + m * 16 + g * 4;
      bf16x4 p;
#pragma unroll
      for (int t = 0; t < 4; ++t) p[t] = tob(acc[m][n][t]);
      *reinterpret_cast<bf16x4*>(&WcT[(size_t)b * 65536 + (size_t)co * 256 + d0]) = p;
    }
}

// --- y[n,co] = Q[n,:] @ Wc + b_out
__global__ __launch_bounds__(256) void k_out(const bf16* __restrict__ Q,
                                             const bf16* __restrict__ WcT,
                                             const float* __restrict__ b_out,
                                             float* __restrict__ y) {
  __shared__ __align__(16) bf16 As[128 * LDP];
  __shared__ __align__(16) bf16 Bs[128 * LDP];
  int bx = blockIdx.x;
  int rb = bx >> 1, cbk = bx & 1;
  int tid = threadIdx.x;
  int lane = tid & 63, w = tid >> 6;
  int wr = w >> 1, wc = w & 1;
  int g = lane >> 4, lr = lane & 15;
  int rowbase = rb * 128;
  int b = rowbase >> 12;
  const bf16* Bb = WcT + (size_t)b * 65536;

  f32x4 acc[4][4];
#pragma unroll
  for (int m = 0; m < 4; ++m)
#pragma unroll
    for (int n = 0; n < 4; ++n) acc[m][n] = (f32x4)0.0f;

  for (int kt = 0; kt < 4; ++kt) {
    int k0 = kt * 64;
    __syncthreads();
#pragma unroll
    for (int r = 0; r < 4; ++r) {
      int idx = r * 2048 + tid * 8;
      int row = idx >> 6, col = idx & 63;
      bf16x8 va = *reinterpret_cast<const bf16x8*>(Q + (size_t)(rowbase + row) * 256 + k0 + col);
      *reinterpret_cast<bf16x8*>(&As[row * LDP + col]) = va;
      bf16x8 vb = *reinterpret_cast<const bf16x8*>(Bb + (size_t)(cbk * 128 + row) * 256 + k0 + col);
      *reinterpret_cast<bf16x8*>(&Bs[row * LDP + col]) = vb;
    }
    __syncthreads();
    compute_tile(As, Bs, acc, wr, wc, lr, g);
  }

  int cbase = cbk * 128 + wc * 64;
#pragma unroll
  for (int m = 0; m < 4; ++m)
#pragma unroll
    for (int n = 0; n < 4; ++n) {
      int col = cbase + n * 16 + lr;
      float bo = b_out[col];
#pragma unroll
      for (int t = 0; t < 4; ++t) {
        int row = rowbase + wr * 64 + m * 16 + g * 4 + t;
        y[(size_t)row * 256 + col] = acc[m][n][t] + bo;
      }
    }
}

extern "C" void kernel_launch(void* const* d_in, const int* in_sizes, int n_in,
                              void* d_out, int out_size, void* d_ws, size_t ws_size,
                              hipStream_t stream) {
  (void)in_sizes; (void)n_in; (void)out_size; (void)ws_size;
  const float* x  = (const float*)d_in[0];
  const float* Wq = (const float*)d_in[1];
  const float* Wo = (const float*)d_in[2];
  const float* bo = (const float*)d_in[3];
  float* y = (float*)d_out;

  char* ws = (char*)d_ws;
  bf16*  Q    = (bf16*)(ws);
  bf16*  Et   = (bf16*)(ws + 33554432);
  bf16*  Vt   = (bf16*)(ws + 67108864);
  float* part = (float*)(ws + 100663296);
  bf16*  WcT  = (bf16*)(ws + 117440512);
  bf16*  WqT  = (bf16*)(ws + 119537664);
  bf16*  WoT  = (bf16*)(ws + 119930880);
  float* S    = (float*)(ws + 120061952);

  k_wt<<<dim3(1024), dim3(256), 0, stream>>>(Wq, Wo, WqT, WoT, S);
  k_qkv<<<dim3(3072), dim3(256), 0, stream>>>(x, WqT, Q, Et, Vt, S);
  k_ctx<<<dim3(256), dim3(256), 0, stream>>>(Et, Vt, part);
  k_wc<<<dim3(64), dim3(256), 0, stream>>>(part, S, WoT, WcT);
  k_out<<<dim3(1024), dim3(256), 0, stream>>>(Q, WcT, bo, y);
}

// Round 7
// 247.061 us; speedup vs baseline: 1.0607x; 1.0607x over previous
//
#include <hip/hip_runtime.h>
#include <hip/hip_bf16.h>

// LinearAttention: B=16, H=W=64 (N=4096 spatial), C=256.
// y[n,co] = sum_d q[n,d] * Wc[b][d,co] + b_out[co]
//   Wc = diag(1/S) * (E^T V) * W_out,  E = exp(k), S[d] = sum_n E[n,d]
// Pipeline: k_prep (x->bf16, transpose weights, zero S) -> k_qkv (GEMM+exp+S)
//           -> k_ctx (8-way split-K E^T V partials) -> k_wc (reduce+scale+GEMM)
//           -> k_out (Q @ Wc + b_out)
// R4: global_load_lds(16B) staging + linear LDS in k_qkv/k_ctx/k_out,
//     XCD-chunked block swizzle, k_ctx split-K 4->8.

typedef __bf16 bf16;
typedef __bf16 bf16x4 __attribute__((ext_vector_type(4)));
typedef __bf16 bf16x8 __attribute__((ext_vector_type(8)));
typedef float  f32x4  __attribute__((ext_vector_type(4)));

#define LDP 72  // padded stride (k_wc only)

__device__ __forceinline__ bf16 tob(float f) { return (bf16)f; }

__device__ __forceinline__ void gl_lds16(const void* g, void* l) {
  __builtin_amdgcn_global_load_lds(
      (const __attribute__((address_space(1))) void*)g,
      (__attribute__((address_space(3))) void*)l, 16, 0, 0);
}

// Stage a 128x64 bf16 tile (row-major, row stride `stride` elems) into linear
// LDS [128][64]. LDS dest = wave-uniform base + lane*16 (gload_lds contract).
__device__ __forceinline__ void stage128x64(const bf16* __restrict__ src,
                                            size_t stride, bf16* lds, int tid) {
#pragma unroll
  for (int r = 0; r < 4; ++r) {
    int e = (r * 256 + tid) * 8;
    int row = e >> 6, col = e & 63;
    gl_lds16(src + (size_t)row * stride + col, lds + e);
  }
}

// 128x128 tile, 4 waves 2x2, wave 64x64 = 4x4 frags, K-step 64. Linear LDS.
__device__ __forceinline__ void compute_tile64(const bf16* As, const bf16* Bs,
                                               f32x4 acc[4][4], int wr, int wc,
                                               int lr, int g) {
#pragma unroll
  for (int ks = 0; ks < 2; ++ks) {
    bf16x8 a[4], b[4];
#pragma unroll
    for (int m = 0; m < 4; ++m)
      a[m] = *reinterpret_cast<const bf16x8*>(&As[(wr * 64 + m * 16 + lr) * 64 + ks * 32 + g * 8]);
#pragma unroll
    for (int n = 0; n < 4; ++n)
      b[n] = *reinterpret_cast<const bf16x8*>(&Bs[(wc * 64 + n * 16 + lr) * 64 + ks * 32 + g * 8]);
#pragma unroll
    for (int m = 0; m < 4; ++m)
#pragma unroll
      for (int n = 0; n < 4; ++n)
        acc[m][n] = __builtin_amdgcn_mfma_f32_16x16x32_bf16(a[m], b[n], acc[m][n], 0, 0, 0);
  }
}

// padded-LDS variant (k_wc: A is reg-staged fp32 reduce+scale)
__device__ __forceinline__ void compute_tileP(const bf16* As, const bf16* Bs,
                                              f32x4 acc[4][4], int wr, int wc,
                                              int lr, int g) {
#pragma unroll
  for (int ks = 0; ks < 2; ++ks) {
    bf16x8 a[4], b[4];
#pragma unroll
    for (int m = 0; m < 4; ++m)
      a[m] = *reinterpret_cast<const bf16x8*>(&As[(wr * 64 + m * 16 + lr) * LDP + ks * 32 + g * 8]);
#pragma unroll
    for (int n = 0; n < 4; ++n)
      b[n] = *reinterpret_cast<const bf16x8*>(&Bs[(wc * 64 + n * 16 + lr) * LDP + ks * 32 + g * 8]);
#pragma unroll
    for (int m = 0; m < 4; ++m)
#pragma unroll
      for (int n = 0; n < 4; ++n)
        acc[m][n] = __builtin_amdgcn_mfma_f32_16x16x32_bf16(a[m], b[n], acc[m][n], 0, 0, 0);
  }
}

// --- prep: xb = bf16(x); WqT[n][k]=Wq[k][n]; WoT[co][e]=Wo[e][co]; S=0 ---
__global__ __launch_bounds__(256) void k_prep(const float* __restrict__ x,
                                              const float* __restrict__ Wq,
                                              const float* __restrict__ Wo,
                                              bf16* __restrict__ xb,
                                              bf16* __restrict__ WqT,
                                              bf16* __restrict__ WoT,
                                              float* __restrict__ S) {
  int b = blockIdx.x, tid = threadIdx.x;
  if (b < 4096) {
    size_t base = (size_t)b * 4096;
#pragma unroll
    for (int r = 0; r < 4; ++r) {
      size_t e = base + r * 1024 + tid * 4;
      float4 v = *reinterpret_cast<const float4*>(x + e);
      bf16x4 p;
      p[0] = tob(v.x); p[1] = tob(v.y); p[2] = tob(v.z); p[3] = tob(v.w);
      *reinterpret_cast<bf16x4*>(xb + e) = p;
    }
    if (b < 16) S[b * 256 + tid] = 0.0f;
  } else {
    int i0 = (b - 4096) * 1024 + tid * 4;
#pragma unroll
    for (int j = 0; j < 4; ++j) {
      int idx = i0 + j;
      if (idx < 196608) {
        int n = idx >> 8, k = idx & 255;
        WqT[idx] = tob(Wq[(size_t)k * 768 + n]);
      } else {
        int i2 = idx - 196608;
        int co = i2 >> 8, e2 = i2 & 255;
        WoT[i2] = tob(Wo[(size_t)e2 * 256 + co]);
      }
    }
  }
}

// --- QKV GEMM: xb[65536,256] @ WqT -> Q[n,c], Et[b,c,n]=exp(k), Vt[b,c,n], S
__global__ __launch_bounds__(256) void k_qkv(const bf16* __restrict__ xb,
                                             const bf16* __restrict__ WqT,
                                             bf16* __restrict__ Q,
                                             bf16* __restrict__ Et,
                                             bf16* __restrict__ Vt,
                                             float* __restrict__ S) {
  __shared__ __align__(16) bf16 As[128 * 64];
  __shared__ __align__(16) bf16 Bs[128 * 64];
  int bx = blockIdx.x;
  int swz = (bx & 7) * 384 + (bx >> 3);   // XCD-chunked: 3072/8=384 per XCD
  int rb = swz / 6, cb = swz % 6;
  int tid = threadIdx.x;
  int lane = tid & 63, w = tid >> 6;
  int wr = w >> 1, wc = w & 1;
  int g = lane >> 4, lr = lane & 15;
  const int rowbase = rb * 128, colbase = cb * 128;

  f32x4 acc[4][4];
#pragma unroll
  for (int m = 0; m < 4; ++m)
#pragma unroll
    for (int n = 0; n < 4; ++n) acc[m][n] = (f32x4)0.0f;

  for (int kt = 0; kt < 4; ++kt) {
    int k0 = kt * 64;
    __syncthreads();
    stage128x64(xb + (size_t)rowbase * 256 + k0, 256, As, tid);
    stage128x64(WqT + (size_t)colbase * 256 + k0, 256, Bs, tid);
    __syncthreads();   // compiler drains vmcnt before barrier -> staging visible
    compute_tile64(As, Bs, acc, wr, wc, lr, g);
  }

  int grow = rowbase + wr * 64;
  int gcol = colbase + wc * 64;
  int sec = gcol >> 8;       // 0=Q 1=K 2=V
  int coff = gcol & 255;
  int b = grow >> 12;
  int nsp = grow & 4095;

  if (sec == 0) {
#pragma unroll
    for (int m = 0; m < 4; ++m)
#pragma unroll
      for (int n = 0; n < 4; ++n) {
        int col = coff + n * 16 + lr;
#pragma unroll
        for (int t = 0; t < 4; ++t) {
          int row = grow + m * 16 + g * 4 + t;
          Q[(size_t)row * 256 + col] = tob(acc[m][n][t]);
        }
      }
  } else {
    bf16* dst = (sec == 1) ? Et : Vt;
    float cs0 = 0.f, cs1 = 0.f, cs2 = 0.f, cs3 = 0.f;
#pragma unroll
    for (int m = 0; m < 4; ++m)
#pragma unroll
      for (int n = 0; n < 4; ++n) {
        int col = coff + n * 16 + lr;
        int nn0 = nsp + m * 16 + g * 4;
        bf16x4 p;
#pragma unroll
        for (int t = 0; t < 4; ++t) {
          float v = acc[m][n][t];
          if (sec == 1) {
            v = expf(v);
            if (n == 0) cs0 += v; else if (n == 1) cs1 += v;
            else if (n == 2) cs2 += v; else cs3 += v;
          }
          p[t] = tob(v);
        }
        *reinterpret_cast<bf16x4*>(&dst[((size_t)(b * 256 + col) << 12) + nn0]) = p;
      }
    if (sec == 1) {
      cs0 += __shfl_xor(cs0, 16); cs0 += __shfl_xor(cs0, 32);
      cs1 += __shfl_xor(cs1, 16); cs1 += __shfl_xor(cs1, 32);
      cs2 += __shfl_xor(cs2, 16); cs2 += __shfl_xor(cs2, 32);
      cs3 += __shfl_xor(cs3, 16); cs3 += __shfl_xor(cs3, 32);
      float v = (g == 0) ? cs0 : (g == 1) ? cs1 : (g == 2) ? cs2 : cs3;
      atomicAdd(&S[b * 256 + coff + g * 16 + lr], v);
    }
  }
}

// --- context partials: part[b][s][d][e] = sum_{n in slice s} Et[d,n]*Vt[e,n]
__global__ __launch_bounds__(256) void k_ctx(const bf16* __restrict__ Et,
                                             const bf16* __restrict__ Vt,
                                             float* __restrict__ part) {
  __shared__ __align__(16) bf16 As[128 * 64];
  __shared__ __align__(16) bf16 Bs[128 * 64];
  int bx = blockIdx.x;
  int swz = (bx & 7) * 64 + (bx >> 3);    // 512/8=64 per XCD
  int tile = swz & 3, dblk = tile >> 1, eblk = tile & 1;
  int s = (swz >> 2) & 7;
  int b = swz >> 5;
  int tid = threadIdx.x;
  int lane = tid & 63, w = tid >> 6;
  int wr = w >> 1, wc = w & 1;
  int g = lane >> 4, lr = lane & 15;

  const bf16* Ab = Et + (((size_t)(b * 256 + dblk * 128)) << 12) + s * 512;
  const bf16* Bb = Vt + (((size_t)(b * 256 + eblk * 128)) << 12) + s * 512;

  f32x4 acc[4][4];
#pragma unroll
  for (int m = 0; m < 4; ++m)
#pragma unroll
    for (int n = 0; n < 4; ++n) acc[m][n] = (f32x4)0.0f;

  for (int kt = 0; kt < 8; ++kt) {
    __syncthreads();
    stage128x64(Ab + kt * 64, 4096, As, tid);
    stage128x64(Bb + kt * 64, 4096, Bs, tid);
    __syncthreads();
    compute_tile64(As, Bs, acc, wr, wc, lr, g);
  }

  float* p = part + (size_t)(b * 8 + s) * 65536;
  int dbase = dblk * 128 + wr * 64;
  int ebase = eblk * 128 + wc * 64;
#pragma unroll
  for (int m = 0; m < 4; ++m)
#pragma unroll
    for (int n = 0; n < 4; ++n)
#pragma unroll
      for (int t = 0; t < 4; ++t)
        p[(size_t)(dbase + m * 16 + g * 4 + t) * 256 + ebase + n * 16 + lr] = acc[m][n][t];
}

// --- Wc^T[b][co][d] = sum_e (sum_s part)/S[d] * Wo[e][co], bf16
__global__ __launch_bounds__(256) void k_wc(const float* __restrict__ part,
                                            const float* __restrict__ S,
                                            const bf16* __restrict__ WoT,
                                            bf16* __restrict__ WcT) {
  __shared__ __align__(16) bf16 As[128 * LDP];
  __shared__ __align__(16) bf16 Bs[128 * LDP];
  int bx = blockIdx.x;
  int b = bx >> 2, dblk = (bx >> 1) & 1, cblk = bx & 1;
  int tid = threadIdx.x;
  int lane = tid & 63, w = tid >> 6;
  int wr = w >> 1, wc = w & 1;
  int g = lane >> 4, lr = lane & 15;
  const float* p0 = part + (size_t)b * 8 * 65536;

  f32x4 acc[4][4];
#pragma unroll
  for (int m = 0; m < 4; ++m)
#pragma unroll
    for (int n = 0; n < 4; ++n) acc[m][n] = (f32x4)0.0f;

  for (int kt = 0; kt < 4; ++kt) {
    int k0 = kt * 64;
    __syncthreads();
#pragma unroll
    for (int r = 0; r < 8; ++r) {
      int idx = r * 1024 + tid * 4;
      int row = idx >> 6, col = idx & 63;
      int d = dblk * 128 + row;
      size_t off = (size_t)d * 256 + k0 + col;
      float4 a0 = *reinterpret_cast<const float4*>(p0 + off);
      float4 a1 = *reinterpret_cast<const float4*>(p0 + 65536 + off);
      float4 a2 = *reinterpret_cast<const float4*>(p0 + 2 * 65536 + off);
      float4 a3 = *reinterpret_cast<const float4*>(p0 + 3 * 65536 + off);
      float4 a4 = *reinterpret_cast<const float4*>(p0 + 4 * 65536 + off);
      float4 a5 = *reinterpret_cast<const float4*>(p0 + 5 * 65536 + off);
      float4 a6 = *reinterpret_cast<const float4*>(p0 + 6 * 65536 + off);
      float4 a7 = *reinterpret_cast<const float4*>(p0 + 7 * 65536 + off);
      float rs = 1.0f / S[b * 256 + d];
      bf16x4 p;
      p[0] = tob((a0.x + a1.x + a2.x + a3.x + a4.x + a5.x + a6.x + a7.x) * rs);
      p[1] = tob((a0.y + a1.y + a2.y + a3.y + a4.y + a5.y + a6.y + a7.y) * rs);
      p[2] = tob((a0.z + a1.z + a2.z + a3.z + a4.z + a5.z + a6.z + a7.z) * rs);
      p[3] = tob((a0.w + a1.w + a2.w + a3.w + a4.w + a5.w + a6.w + a7.w) * rs);
      *reinterpret_cast<bf16x4*>(&As[row * LDP + col]) = p;
    }
#pragma unroll
    for (int r = 0; r < 4; ++r) {
      int idx = r * 2048 + tid * 8;
      int row = idx >> 6, col = idx & 63;
      bf16x8 v = *reinterpret_cast<const bf16x8*>(WoT + (size_t)(cblk * 128 + row) * 256 + k0 + col);
      *reinterpret_cast<bf16x8*>(&Bs[row * LDP + col]) = v;
    }
    __syncthreads();
    compute_tileP(As, Bs, acc, wr, wc, lr, g);
  }

  int dbase = dblk * 128 + wr * 64;
  int cbase = cblk * 128 + wc * 64;
#pragma unroll
  for (int m = 0; m < 4; ++m)
#pragma unroll
    for (int n = 0; n < 4; ++n) {
      int co = cbase + n * 16 + lr;
      int d0 = dbase + m * 16 + g * 4;
      bf16x4 p;
#pragma unroll
      for (int t = 0; t < 4; ++t) p[t] = tob(acc[m][n][t]);
      *reinterpret_cast<bf16x4*>(&WcT[(size_t)b * 65536 + (size_t)co * 256 + d0]) = p;
    }
}

// --- y[n,co] = Q[n,:] @ Wc + b_out
__global__ __launch_bounds__(256) void k_out(const bf16* __restrict__ Q,
                                             const bf16* __restrict__ WcT,
                                             const float* __restrict__ b_out,
                                             float* __restrict__ y) {
  __shared__ __align__(16) bf16 As[128 * 64];
  __shared__ __align__(16) bf16 Bs[128 * 64];
  int bx = blockIdx.x;
  int swz = (bx & 7) * 128 + (bx >> 3);   // 1024/8=128 per XCD
  int rb = swz >> 1, cbk = swz & 1;
  int tid = threadIdx.x;
  int lane = tid & 63, w = tid >> 6;
  int wr = w >> 1, wc = w & 1;
  int g = lane >> 4, lr = lane & 15;
  int rowbase = rb * 128;
  int b = rowbase >> 12;
  const bf16* Bb = WcT + (size_t)b * 65536;

  f32x4 acc[4][4];
#pragma unroll
  for (int m = 0; m < 4; ++m)
#pragma unroll
    for (int n = 0; n < 4; ++n) acc[m][n] = (f32x4)0.0f;

  for (int kt = 0; kt < 4; ++kt) {
    int k0 = kt * 64;
    __syncthreads();
    stage128x64(Q + (size_t)rowbase * 256 + k0, 256, As, tid);
    stage128x64(Bb + (size_t)(cbk * 128) * 256 + k0, 256, Bs, tid);
    __syncthreads();
    compute_tile64(As, Bs, acc, wr, wc, lr, g);
  }

  int cbase = cbk * 128 + wc * 64;
#pragma unroll
  for (int m = 0; m < 4; ++m)
#pragma unroll
    for (int n = 0; n < 4; ++n) {
      int col = cbase + n * 16 + lr;
      float bo = b_out[col];
#pragma unroll
      for (int t = 0; t < 4; ++t) {
        int row = rowbase + wr * 64 + m * 16 + g * 4 + t;
        y[(size_t)row * 256 + col] = acc[m][n][t] + bo;
      }
    }
}

extern "C" void kernel_launch(void* const* d_in, const int* in_sizes, int n_in,
                              void* d_out, int out_size, void* d_ws, size_t ws_size,
                              hipStream_t stream) {
  (void)in_sizes; (void)n_in; (void)out_size; (void)ws_size;
  const float* x  = (const float*)d_in[0];
  const float* Wq = (const float*)d_in[1];
  const float* Wo = (const float*)d_in[2];
  const float* bo = (const float*)d_in[3];
  float* y = (float*)d_out;

  char* ws = (char*)d_ws;
  bf16*  Q    = (bf16*)(ws);                    // 33.55 MB
  bf16*  Et   = (bf16*)(ws + 33554432);         // 33.55 MB
  bf16*  Vt   = (bf16*)(ws + 67108864);         // 33.55 MB
  bf16*  xb   = (bf16*)(ws + 100663296);        // 33.55 MB (dead after k_qkv)
  float* part = (float*)(ws + 100663296);       // aliases xb (live after k_qkv)
  bf16*  WcT  = (bf16*)(ws + 134217728);        // 2 MB
  bf16*  WqT  = (bf16*)(ws + 136314880);        // 384 KB
  bf16*  WoT  = (bf16*)(ws + 136708096);        // 128 KB
  float* S    = (float*)(ws + 136839168);       // 16 KB

  k_prep<<<dim3(4352), dim3(256), 0, stream>>>(x, Wq, Wo, xb, WqT, WoT, S);
  k_qkv<<<dim3(3072), dim3(256), 0, stream>>>(xb, WqT, Q, Et, Vt, S);
  k_ctx<<<dim3(512), dim3(256), 0, stream>>>(Et, Vt, part);
  k_wc<<<dim3(64), dim3(256), 0, stream>>>(part, S, WoT, WcT);
  k_out<<<dim3(1024), dim3(256), 0, stream>>>(Q, WcT, bo, y);
}

// Round 8
// 232.550 us; speedup vs baseline: 1.1269x; 1.0624x over previous
//
#include <hip/hip_runtime.h>
#include <hip/hip_bf16.h>

// LinearAttention: B=16, H=W=64 (N=4096 spatial), C=256.
// y[n,co] = sum_d q[n,d] * Wc[b][d,co] + b_out[co]
//   Wc = diag(1/S) * (E^T V) * W_out,  E = exp(k), S[d] = sum_n E[n,d]
// R7: (1) both-sides XOR swizzle on LDS tiles (linear gload_lds dest +
//     inverse-swizzled global source + swizzled ds_read) -> bank-conflict-free;
//     (2) double-buffered 1-barrier K-loop (static buffer names, prefetch
//     issued before compute, single syncthreads drains vmcnt after compute).

typedef __bf16 bf16;
typedef __bf16 bf16x4 __attribute__((ext_vector_type(4)));
typedef __bf16 bf16x8 __attribute__((ext_vector_type(8)));
typedef float  f32x4  __attribute__((ext_vector_type(4)));

#define LDP 72  // padded stride (k_wc only)

__device__ __forceinline__ bf16 tob(float f) { return (bf16)f; }

__device__ __forceinline__ void gl_lds16(const void* g, void* l) {
  __builtin_amdgcn_global_load_lds(
      (const __attribute__((address_space(1))) void*)g,
      (__attribute__((address_space(3))) void*)l, 16, 0, 0);
}

// Stage a 128x64 bf16 tile into linear LDS with inverse-swizzled SOURCE:
// LDS slot (row, c16) holds global (row, c16 ^ (row&7)). Reads apply the same
// XOR -> involution cancels. gload_lds dest stays linear (lane*16 contract).
__device__ __forceinline__ void stage_swz(const bf16* __restrict__ src,
                                          size_t stride, bf16* lds, int tid) {
#pragma unroll
  for (int r = 0; r < 4; ++r) {
    int si = r * 256 + tid;           // 16B-slot index 0..1023
    int row = si >> 3, c16 = si & 7;
    int gcol = (c16 ^ (row & 7)) << 3;
    gl_lds16(src + (size_t)row * stride + gcol, lds + si * 8);
  }
}

// 128x128 tile, 4 waves 2x2, wave 64x64 = 4x4 frags, K-step 64.
// Swizzled read: slot = (ks*4+g) ^ (row&7); row&7 == lr&7 here.
__device__ __forceinline__ void compute_tile_swz(const bf16* As, const bf16* Bs,
                                                 f32x4 acc[4][4], int wr, int wc,
                                                 int lr, int g) {
#pragma unroll
  for (int ks = 0; ks < 2; ++ks) {
    int slot = ((ks * 4 + g) ^ (lr & 7)) * 8;
    bf16x8 a[4], b[4];
#pragma unroll
    for (int m = 0; m < 4; ++m)
      a[m] = *reinterpret_cast<const bf16x8*>(&As[(wr * 64 + m * 16 + lr) * 64 + slot]);
#pragma unroll
    for (int n = 0; n < 4; ++n)
      b[n] = *reinterpret_cast<const bf16x8*>(&Bs[(wc * 64 + n * 16 + lr) * 64 + slot]);
#pragma unroll
    for (int m = 0; m < 4; ++m)
#pragma unroll
      for (int n = 0; n < 4; ++n)
        acc[m][n] = __builtin_amdgcn_mfma_f32_16x16x32_bf16(a[m], b[n], acc[m][n], 0, 0, 0);
  }
}

// padded-LDS variant (k_wc: A is reg-staged fp32 reduce+scale)
__device__ __forceinline__ void compute_tileP(const bf16* As, const bf16* Bs,
                                              f32x4 acc[4][4], int wr, int wc,
                                              int lr, int g) {
#pragma unroll
  for (int ks = 0; ks < 2; ++ks) {
    bf16x8 a[4], b[4];
#pragma unroll
    for (int m = 0; m < 4; ++m)
      a[m] = *reinterpret_cast<const bf16x8*>(&As[(wr * 64 + m * 16 + lr) * LDP + ks * 32 + g * 8]);
#pragma unroll
    for (int n = 0; n < 4; ++n)
      b[n] = *reinterpret_cast<const bf16x8*>(&Bs[(wc * 64 + n * 16 + lr) * LDP + ks * 32 + g * 8]);
#pragma unroll
    for (int m = 0; m < 4; ++m)
#pragma unroll
      for (int n = 0; n < 4; ++n)
        acc[m][n] = __builtin_amdgcn_mfma_f32_16x16x32_bf16(a[m], b[n], acc[m][n], 0, 0, 0);
  }
}

// --- prep: xb = bf16(x); WqT[n][k]=Wq[k][n]; WoT[co][e]=Wo[e][co]; S=0 ---
__global__ __launch_bounds__(256) void k_prep(const float* __restrict__ x,
                                              const float* __restrict__ Wq,
                                              const float* __restrict__ Wo,
                                              bf16* __restrict__ xb,
                                              bf16* __restrict__ WqT,
                                              bf16* __restrict__ WoT,
                                              float* __restrict__ S) {
  int b = blockIdx.x, tid = threadIdx.x;
  if (b < 4096) {
    size_t base = (size_t)b * 4096;
#pragma unroll
    for (int r = 0; r < 4; ++r) {
      size_t e = base + r * 1024 + tid * 4;
      float4 v = *reinterpret_cast<const float4*>(x + e);
      bf16x4 p;
      p[0] = tob(v.x); p[1] = tob(v.y); p[2] = tob(v.z); p[3] = tob(v.w);
      *reinterpret_cast<bf16x4*>(xb + e) = p;
    }
    if (b < 16) S[b * 256 + tid] = 0.0f;
  } else {
    int i0 = (b - 4096) * 1024 + tid * 4;
#pragma unroll
    for (int j = 0; j < 4; ++j) {
      int idx = i0 + j;
      if (idx < 196608) {
        int n = idx >> 8, k = idx & 255;
        WqT[idx] = tob(Wq[(size_t)k * 768 + n]);
      } else {
        int i2 = idx - 196608;
        int co = i2 >> 8, e2 = i2 & 255;
        WoT[i2] = tob(Wo[(size_t)e2 * 256 + co]);
      }
    }
  }
}

// --- QKV GEMM: xb[65536,256] @ WqT -> Q[n,c], Et[b,c,n]=exp(k), Vt[b,c,n], S
__global__ __launch_bounds__(256) void k_qkv(const bf16* __restrict__ xb,
                                             const bf16* __restrict__ WqT,
                                             bf16* __restrict__ Q,
                                             bf16* __restrict__ Et,
                                             bf16* __restrict__ Vt,
                                             float* __restrict__ S) {
  __shared__ __align__(16) bf16 As0[8192], Bs0[8192], As1[8192], Bs1[8192];
  int bx = blockIdx.x;
  int swz = (bx & 7) * 384 + (bx >> 3);   // XCD-chunked: 3072/8=384 per XCD
  int rb = swz / 6, cb = swz % 6;
  int tid = threadIdx.x;
  int lane = tid & 63, w = tid >> 6;
  int wr = w >> 1, wc = w & 1;
  int g = lane >> 4, lr = lane & 15;
  const int rowbase = rb * 128, colbase = cb * 128;
  const bf16* Ab = xb + (size_t)rowbase * 256;
  const bf16* Bb = WqT + (size_t)colbase * 256;

  f32x4 acc[4][4];
#pragma unroll
  for (int m = 0; m < 4; ++m)
#pragma unroll
    for (int n = 0; n < 4; ++n) acc[m][n] = (f32x4)0.0f;

  stage_swz(Ab, 256, As0, tid);
  stage_swz(Bb, 256, Bs0, tid);
  __syncthreads();
#pragma unroll
  for (int kp = 0; kp < 2; ++kp) {
    int kt = kp * 2;
    stage_swz(Ab + (kt + 1) * 64, 256, As1, tid);
    stage_swz(Bb + (kt + 1) * 64, 256, Bs1, tid);
    compute_tile_swz(As0, Bs0, acc, wr, wc, lr, g);
    __syncthreads();
    if (kt + 2 < 4) {
      stage_swz(Ab + (kt + 2) * 64, 256, As0, tid);
      stage_swz(Bb + (kt + 2) * 64, 256, Bs0, tid);
    }
    compute_tile_swz(As1, Bs1, acc, wr, wc, lr, g);
    if (kt + 2 < 4) __syncthreads();
  }

  int grow = rowbase + wr * 64;
  int gcol = colbase + wc * 64;
  int sec = gcol >> 8;       // 0=Q 1=K 2=V
  int coff = gcol & 255;
  int b = grow >> 12;
  int nsp = grow & 4095;

  if (sec == 0) {
#pragma unroll
    for (int m = 0; m < 4; ++m)
#pragma unroll
      for (int n = 0; n < 4; ++n) {
        int col = coff + n * 16 + lr;
#pragma unroll
        for (int t = 0; t < 4; ++t) {
          int row = grow + m * 16 + g * 4 + t;
          Q[(size_t)row * 256 + col] = tob(acc[m][n][t]);
        }
      }
  } else {
    bf16* dst = (sec == 1) ? Et : Vt;
    float cs0 = 0.f, cs1 = 0.f, cs2 = 0.f, cs3 = 0.f;
#pragma unroll
    for (int m = 0; m < 4; ++m)
#pragma unroll
      for (int n = 0; n < 4; ++n) {
        int col = coff + n * 16 + lr;
        int nn0 = nsp + m * 16 + g * 4;
        bf16x4 p;
#pragma unroll
        for (int t = 0; t < 4; ++t) {
          float v = acc[m][n][t];
          if (sec == 1) {
            v = expf(v);
            if (n == 0) cs0 += v; else if (n == 1) cs1 += v;
            else if (n == 2) cs2 += v; else cs3 += v;
          }
          p[t] = tob(v);
        }
        *reinterpret_cast<bf16x4*>(&dst[((size_t)(b * 256 + col) << 12) + nn0]) = p;
      }
    if (sec == 1) {
      cs0 += __shfl_xor(cs0, 16); cs0 += __shfl_xor(cs0, 32);
      cs1 += __shfl_xor(cs1, 16); cs1 += __shfl_xor(cs1, 32);
      cs2 += __shfl_xor(cs2, 16); cs2 += __shfl_xor(cs2, 32);
      cs3 += __shfl_xor(cs3, 16); cs3 += __shfl_xor(cs3, 32);
      float v = (g == 0) ? cs0 : (g == 1) ? cs1 : (g == 2) ? cs2 : cs3;
      atomicAdd(&S[b * 256 + coff + g * 16 + lr], v);
    }
  }
}

// --- context partials: part[b][s][d][e] = sum_{n in slice s} Et[d,n]*Vt[e,n]
__global__ __launch_bounds__(256) void k_ctx(const bf16* __restrict__ Et,
                                             const bf16* __restrict__ Vt,
                                             float* __restrict__ part) {
  __shared__ __align__(16) bf16 As0[8192], Bs0[8192], As1[8192], Bs1[8192];
  int bx = blockIdx.x;
  int swz = (bx & 7) * 64 + (bx >> 3);    // 512/8=64 per XCD
  int tile = swz & 3, dblk = tile >> 1, eblk = tile & 1;
  int s = (swz >> 2) & 7;
  int b = swz >> 5;
  int tid = threadIdx.x;
  int lane = tid & 63, w = tid >> 6;
  int wr = w >> 1, wc = w & 1;
  int g = lane >> 4, lr = lane & 15;

  const bf16* Ab = Et + (((size_t)(b * 256 + dblk * 128)) << 12) + s * 512;
  const bf16* Bb = Vt + (((size_t)(b * 256 + eblk * 128)) << 12) + s * 512;

  f32x4 acc[4][4];
#pragma unroll
  for (int m = 0; m < 4; ++m)
#pragma unroll
    for (int n = 0; n < 4; ++n) acc[m][n] = (f32x4)0.0f;

  stage_swz(Ab, 4096, As0, tid);
  stage_swz(Bb, 4096, Bs0, tid);
  __syncthreads();
#pragma unroll
  for (int kp = 0; kp < 4; ++kp) {
    int kt = kp * 2;
    stage_swz(Ab + (kt + 1) * 64, 4096, As1, tid);
    stage_swz(Bb + (kt + 1) * 64, 4096, Bs1, tid);
    compute_tile_swz(As0, Bs0, acc, wr, wc, lr, g);
    __syncthreads();
    if (kt + 2 < 8) {
      stage_swz(Ab + (kt + 2) * 64, 4096, As0, tid);
      stage_swz(Bb + (kt + 2) * 64, 4096, Bs0, tid);
    }
    compute_tile_swz(As1, Bs1, acc, wr, wc, lr, g);
    if (kt + 2 < 8) __syncthreads();
  }

  float* p = part + (size_t)(b * 8 + s) * 65536;
  int dbase = dblk * 128 + wr * 64;
  int ebase = eblk * 128 + wc * 64;
#pragma unroll
  for (int m = 0; m < 4; ++m)
#pragma unroll
    for (int n = 0; n < 4; ++n)
#pragma unroll
      for (int t = 0; t < 4; ++t)
        p[(size_t)(dbase + m * 16 + g * 4 + t) * 256 + ebase + n * 16 + lr] = acc[m][n][t];
}

// --- Wc^T[b][co][d] = sum_e (sum_s part)/S[d] * Wo[e][co], bf16
__global__ __launch_bounds__(256) void k_wc(const float* __restrict__ part,
                                            const float* __restrict__ S,
                                            const bf16* __restrict__ WoT,
                                            bf16* __restrict__ WcT) {
  __shared__ __align__(16) bf16 As[128 * LDP];
  __shared__ __align__(16) bf16 Bs[128 * LDP];
  int bx = blockIdx.x;
  int b = bx >> 2, dblk = (bx >> 1) & 1, cblk = bx & 1;
  int tid = threadIdx.x;
  int lane = tid & 63, w = tid >> 6;
  int wr = w >> 1, wc = w & 1;
  int g = lane >> 4, lr = lane & 15;
  const float* p0 = part + (size_t)b * 8 * 65536;

  f32x4 acc[4][4];
#pragma unroll
  for (int m = 0; m < 4; ++m)
#pragma unroll
    for (int n = 0; n < 4; ++n) acc[m][n] = (f32x4)0.0f;

  for (int kt = 0; kt < 4; ++kt) {
    int k0 = kt * 64;
    __syncthreads();
#pragma unroll
    for (int r = 0; r < 8; ++r) {
      int idx = r * 1024 + tid * 4;
      int row = idx >> 6, col = idx & 63;
      int d = dblk * 128 + row;
      size_t off = (size_t)d * 256 + k0 + col;
      float4 a0 = *reinterpret_cast<const float4*>(p0 + off);
      float4 a1 = *reinterpret_cast<const float4*>(p0 + 65536 + off);
      float4 a2 = *reinterpret_cast<const float4*>(p0 + 2 * 65536 + off);
      float4 a3 = *reinterpret_cast<const float4*>(p0 + 3 * 65536 + off);
      float4 a4 = *reinterpret_cast<const float4*>(p0 + 4 * 65536 + off);
      float4 a5 = *reinterpret_cast<const float4*>(p0 + 5 * 65536 + off);
      float4 a6 = *reinterpret_cast<const float4*>(p0 + 6 * 65536 + off);
      float4 a7 = *reinterpret_cast<const float4*>(p0 + 7 * 65536 + off);
      float rs = 1.0f / S[b * 256 + d];
      bf16x4 p;
      p[0] = tob((a0.x + a1.x + a2.x + a3.x + a4.x + a5.x + a6.x + a7.x) * rs);
      p[1] = tob((a0.y + a1.y + a2.y + a3.y + a4.y + a5.y + a6.y + a7.y) * rs);
      p[2] = tob((a0.z + a1.z + a2.z + a3.z + a4.z + a5.z + a6.z + a7.z) * rs);
      p[3] = tob((a0.w + a1.w + a2.w + a3.w + a4.w + a5.w + a6.w + a7.w) * rs);
      *reinterpret_cast<bf16x4*>(&As[row * LDP + col]) = p;
    }
#pragma unroll
    for (int r = 0; r < 4; ++r) {
      int idx = r * 2048 + tid * 8;
      int row = idx >> 6, col = idx & 63;
      bf16x8 v = *reinterpret_cast<const bf16x8*>(WoT + (size_t)(cblk * 128 + row) * 256 + k0 + col);
      *reinterpret_cast<bf16x8*>(&Bs[row * LDP + col]) = v;
    }
    __syncthreads();
    compute_tileP(As, Bs, acc, wr, wc, lr, g);
  }

  int dbase = dblk * 128 + wr * 64;
  int cbase = cblk * 128 + wc * 64;
#pragma unroll
  for (int m = 0; m < 4; ++m)
#pragma unroll
    for (int n = 0; n < 4; ++n) {
      int co = cbase + n * 16 + lr;
      int d0 = dbase + m * 16 + g * 4;
      bf16x4 p;
#pragma unroll
      for (int t = 0; t < 4; ++t) p[t] = tob(acc[m][n][t]);
      *reinterpret_cast<bf16x4*>(&WcT[(size_t)b * 65536 + (size_t)co * 256 + d0]) = p;
    }
}

// --- y[n,co] = Q[n,:] @ Wc + b_out
__global__ __launch_bounds__(256) void k_out(const bf16* __restrict__ Q,
                                             const bf16* __restrict__ WcT,
                                             const float* __restrict__ b_out,
                                             float* __restrict__ y) {
  __shared__ __align__(16) bf16 As0[8192], Bs0[8192], As1[8192], Bs1[8192];
  int bx = blockIdx.x;
  int swz = (bx & 7) * 128 + (bx >> 3);   // 1024/8=128 per XCD
  int rb = swz >> 1, cbk = swz & 1;
  int tid = threadIdx.x;
  int lane = tid & 63, w = tid >> 6;
  int wr = w >> 1, wc = w & 1;
  int g = lane >> 4, lr = lane & 15;
  int rowbase = rb * 128;
  int b = rowbase >> 12;
  const bf16* Ab = Q + (size_t)rowbase * 256;
  const bf16* Bb = WcT + (size_t)b * 65536 + (size_t)(cbk * 128) * 256;

  f32x4 acc[4][4];
#pragma unroll
  for (int m = 0; m < 4; ++m)
#pragma unroll
    for (int n = 0; n < 4; ++n) acc[m][n] = (f32x4)0.0f;

  stage_swz(Ab, 256, As0, tid);
  stage_swz(Bb, 256, Bs0, tid);
  __syncthreads();
#pragma unroll
  for (int kp = 0; kp < 2; ++kp) {
    int kt = kp * 2;
    stage_swz(Ab + (kt + 1) * 64, 256, As1, tid);
    stage_swz(Bb + (kt + 1) * 64, 256, Bs1, tid);
    compute_tile_swz(As0, Bs0, acc, wr, wc, lr, g);
    __syncthreads();
    if (kt + 2 < 4) {
      stage_swz(Ab + (kt + 2) * 64, 256, As0, tid);
      stage_swz(Bb + (kt + 2) * 64, 256, Bs0, tid);
    }
    compute_tile_swz(As1, Bs1, acc, wr, wc, lr, g);
    if (kt + 2 < 4) __syncthreads();
  }

  int cbase = cbk * 128 + wc * 64;
#pragma unroll
  for (int m = 0; m < 4; ++m)
#pragma unroll
    for (int n = 0; n < 4; ++n) {
      int col = cbase + n * 16 + lr;
      float bo = b_out[col];
#pragma unroll
      for (int t = 0; t < 4; ++t) {
        int row = rowbase + wr * 64 + m * 16 + g * 4 + t;
        y[(size_t)row * 256 + col] = acc[m][n][t] + bo;
      }
    }
}

extern "C" void kernel_launch(void* const* d_in, const int* in_sizes, int n_in,
                              void* d_out, int out_size, void* d_ws, size_t ws_size,
                              hipStream_t stream) {
  (void)in_sizes; (void)n_in; (void)out_size; (void)ws_size;
  const float* x  = (const float*)d_in[0];
  const float* Wq = (const float*)d_in[1];
  const float* Wo = (const float*)d_in[2];
  const float* bo = (const float*)d_in[3];
  float* y = (float*)d_out;

  char* ws = (char*)d_ws;
  bf16*  Q    = (bf16*)(ws);                    // 33.55 MB
  bf16*  Et   = (bf16*)(ws + 33554432);         // 33.55 MB
  bf16*  Vt   = (bf16*)(ws + 67108864);         // 33.55 MB
  bf16*  xb   = (bf16*)(ws + 100663296);        // 33.55 MB (dead after k_qkv)
  float* part = (float*)(ws + 100663296);       // aliases xb (live after k_qkv)
  bf16*  WcT  = (bf16*)(ws + 134217728);        // 2 MB
  bf16*  WqT  = (bf16*)(ws + 136314880);        // 384 KB
  bf16*  WoT  = (bf16*)(ws + 136708096);        // 128 KB
  float* S    = (float*)(ws + 136839168);       // 16 KB

  k_prep<<<dim3(4352), dim3(256), 0, stream>>>(x, Wq, Wo, xb, WqT, WoT, S);
  k_qkv<<<dim3(3072), dim3(256), 0, stream>>>(xb, WqT, Q, Et, Vt, S);
  k_ctx<<<dim3(512), dim3(256), 0, stream>>>(Et, Vt, part);
  k_wc<<<dim3(64), dim3(256), 0, stream>>>(part, S, WoT, WcT);
  k_out<<<dim3(1024), dim3(256), 0, stream>>>(Q, WcT, bo, y);
}

// Round 9
// 228.077 us; speedup vs baseline: 1.1490x; 1.0196x over previous
//
#include <hip/hip_runtime.h>
#include <hip/hip_bf16.h>

// LinearAttention: B=16, H=W=64 (N=4096 spatial), C=256.
// y[n,co] = sum_d q[n,d] * Wc[b][d,co] + b_out[co]
//   Wc = diag(1/S) * (E^T V) * W_out,  E = exp(k), S[d] = sum_n E[n,d]
// R9: bf16 split-K partials (halve part traffic); k_wc 64->128 blocks
//     (128d x 64co tile, wave 64x32). k_qkv/k_ctx keep R7 swizzle+dbuf.

typedef __bf16 bf16;
typedef __bf16 bf16x4 __attribute__((ext_vector_type(4)));
typedef __bf16 bf16x8 __attribute__((ext_vector_type(8)));
typedef float  f32x4  __attribute__((ext_vector_type(4)));

#define LDP 72  // padded stride (k_wc only)

__device__ __forceinline__ bf16 tob(float f) { return (bf16)f; }

__device__ __forceinline__ void gl_lds16(const void* g, void* l) {
  __builtin_amdgcn_global_load_lds(
      (const __attribute__((address_space(1))) void*)g,
      (__attribute__((address_space(3))) void*)l, 16, 0, 0);
}

// Stage a 128x64 bf16 tile into linear LDS with inverse-swizzled SOURCE:
// LDS slot (row, c16) holds global (row, c16 ^ (row&7)). Reads apply the same
// XOR -> involution cancels. gload_lds dest stays linear (lane*16 contract).
__device__ __forceinline__ void stage_swz(const bf16* __restrict__ src,
                                          size_t stride, bf16* lds, int tid) {
#pragma unroll
  for (int r = 0; r < 4; ++r) {
    int si = r * 256 + tid;           // 16B-slot index 0..1023
    int row = si >> 3, c16 = si & 7;
    int gcol = (c16 ^ (row & 7)) << 3;
    gl_lds16(src + (size_t)row * stride + gcol, lds + si * 8);
  }
}

// 128x128 tile, 4 waves 2x2, wave 64x64 = 4x4 frags, K-step 64.
// Swizzled read: slot = (ks*4+g) ^ (row&7); row&7 == lr&7 here.
__device__ __forceinline__ void compute_tile_swz(const bf16* As, const bf16* Bs,
                                                 f32x4 acc[4][4], int wr, int wc,
                                                 int lr, int g) {
#pragma unroll
  for (int ks = 0; ks < 2; ++ks) {
    int slot = ((ks * 4 + g) ^ (lr & 7)) * 8;
    bf16x8 a[4], b[4];
#pragma unroll
    for (int m = 0; m < 4; ++m)
      a[m] = *reinterpret_cast<const bf16x8*>(&As[(wr * 64 + m * 16 + lr) * 64 + slot]);
#pragma unroll
    for (int n = 0; n < 4; ++n)
      b[n] = *reinterpret_cast<const bf16x8*>(&Bs[(wc * 64 + n * 16 + lr) * 64 + slot]);
#pragma unroll
    for (int m = 0; m < 4; ++m)
#pragma unroll
      for (int n = 0; n < 4; ++n)
        acc[m][n] = __builtin_amdgcn_mfma_f32_16x16x32_bf16(a[m], b[n], acc[m][n], 0, 0, 0);
  }
}

// padded-LDS 64x32-wave variant (k_wc): A 128 rows, B 64 rows, acc[4][2]
__device__ __forceinline__ void compute_tileP2(const bf16* As, const bf16* Bs,
                                               f32x4 acc[4][2], int wr, int wc,
                                               int lr, int g) {
#pragma unroll
  for (int ks = 0; ks < 2; ++ks) {
    bf16x8 a[4], b[2];
#pragma unroll
    for (int m = 0; m < 4; ++m)
      a[m] = *reinterpret_cast<const bf16x8*>(&As[(wr * 64 + m * 16 + lr) * LDP + ks * 32 + g * 8]);
#pragma unroll
    for (int n = 0; n < 2; ++n)
      b[n] = *reinterpret_cast<const bf16x8*>(&Bs[(wc * 32 + n * 16 + lr) * LDP + ks * 32 + g * 8]);
#pragma unroll
    for (int m = 0; m < 4; ++m)
#pragma unroll
      for (int n = 0; n < 2; ++n)
        acc[m][n] = __builtin_amdgcn_mfma_f32_16x16x32_bf16(a[m], b[n], acc[m][n], 0, 0, 0);
  }
}

// --- prep: xb = bf16(x); WqT[n][k]=Wq[k][n]; WoT[co][e]=Wo[e][co]; S=0 ---
__global__ __launch_bounds__(256) void k_prep(const float* __restrict__ x,
                                              const float* __restrict__ Wq,
                                              const float* __restrict__ Wo,
                                              bf16* __restrict__ xb,
                                              bf16* __restrict__ WqT,
                                              bf16* __restrict__ WoT,
                                              float* __restrict__ S) {
  int b = blockIdx.x, tid = threadIdx.x;
  if (b < 4096) {
    size_t base = (size_t)b * 4096;
#pragma unroll
    for (int r = 0; r < 4; ++r) {
      size_t e = base + r * 1024 + tid * 4;
      float4 v = *reinterpret_cast<const float4*>(x + e);
      bf16x4 p;
      p[0] = tob(v.x); p[1] = tob(v.y); p[2] = tob(v.z); p[3] = tob(v.w);
      *reinterpret_cast<bf16x4*>(xb + e) = p;
    }
    if (b < 16) S[b * 256 + tid] = 0.0f;
  } else {
    int i0 = (b - 4096) * 1024 + tid * 4;
#pragma unroll
    for (int j = 0; j < 4; ++j) {
      int idx = i0 + j;
      if (idx < 196608) {
        int n = idx >> 8, k = idx & 255;
        WqT[idx] = tob(Wq[(size_t)k * 768 + n]);
      } else {
        int i2 = idx - 196608;
        int co = i2 >> 8, e2 = i2 & 255;
        WoT[i2] = tob(Wo[(size_t)e2 * 256 + co]);
      }
    }
  }
}

// --- QKV GEMM: xb[65536,256] @ WqT -> Q[n,c], Et[b,c,n]=exp(k), Vt[b,c,n], S
__global__ __launch_bounds__(256) void k_qkv(const bf16* __restrict__ xb,
                                             const bf16* __restrict__ WqT,
                                             bf16* __restrict__ Q,
                                             bf16* __restrict__ Et,
                                             bf16* __restrict__ Vt,
                                             float* __restrict__ S) {
  __shared__ __align__(16) bf16 As0[8192], Bs0[8192], As1[8192], Bs1[8192];
  int bx = blockIdx.x;
  int swz = (bx & 7) * 384 + (bx >> 3);   // XCD-chunked: 3072/8=384 per XCD
  int rb = swz / 6, cb = swz % 6;
  int tid = threadIdx.x;
  int lane = tid & 63, w = tid >> 6;
  int wr = w >> 1, wc = w & 1;
  int g = lane >> 4, lr = lane & 15;
  const int rowbase = rb * 128, colbase = cb * 128;
  const bf16* Ab = xb + (size_t)rowbase * 256;
  const bf16* Bb = WqT + (size_t)colbase * 256;

  f32x4 acc[4][4];
#pragma unroll
  for (int m = 0; m < 4; ++m)
#pragma unroll
    for (int n = 0; n < 4; ++n) acc[m][n] = (f32x4)0.0f;

  stage_swz(Ab, 256, As0, tid);
  stage_swz(Bb, 256, Bs0, tid);
  __syncthreads();
#pragma unroll
  for (int kp = 0; kp < 2; ++kp) {
    int kt = kp * 2;
    stage_swz(Ab + (kt + 1) * 64, 256, As1, tid);
    stage_swz(Bb + (kt + 1) * 64, 256, Bs1, tid);
    compute_tile_swz(As0, Bs0, acc, wr, wc, lr, g);
    __syncthreads();
    if (kt + 2 < 4) {
      stage_swz(Ab + (kt + 2) * 64, 256, As0, tid);
      stage_swz(Bb + (kt + 2) * 64, 256, Bs0, tid);
    }
    compute_tile_swz(As1, Bs1, acc, wr, wc, lr, g);
    if (kt + 2 < 4) __syncthreads();
  }

  int grow = rowbase + wr * 64;
  int gcol = colbase + wc * 64;
  int sec = gcol >> 8;       // 0=Q 1=K 2=V
  int coff = gcol & 255;
  int b = grow >> 12;
  int nsp = grow & 4095;

  if (sec == 0) {
#pragma unroll
    for (int m = 0; m < 4; ++m)
#pragma unroll
      for (int n = 0; n < 4; ++n) {
        int col = coff + n * 16 + lr;
#pragma unroll
        for (int t = 0; t < 4; ++t) {
          int row = grow + m * 16 + g * 4 + t;
          Q[(size_t)row * 256 + col] = tob(acc[m][n][t]);
        }
      }
  } else {
    bf16* dst = (sec == 1) ? Et : Vt;
    float cs0 = 0.f, cs1 = 0.f, cs2 = 0.f, cs3 = 0.f;
#pragma unroll
    for (int m = 0; m < 4; ++m)
#pragma unroll
      for (int n = 0; n < 4; ++n) {
        int col = coff + n * 16 + lr;
        int nn0 = nsp + m * 16 + g * 4;
        bf16x4 p;
#pragma unroll
        for (int t = 0; t < 4; ++t) {
          float v = acc[m][n][t];
          if (sec == 1) {
            v = expf(v);
            if (n == 0) cs0 += v; else if (n == 1) cs1 += v;
            else if (n == 2) cs2 += v; else cs3 += v;
          }
          p[t] = tob(v);
        }
        *reinterpret_cast<bf16x4*>(&dst[((size_t)(b * 256 + col) << 12) + nn0]) = p;
      }
    if (sec == 1) {
      cs0 += __shfl_xor(cs0, 16); cs0 += __shfl_xor(cs0, 32);
      cs1 += __shfl_xor(cs1, 16); cs1 += __shfl_xor(cs1, 32);
      cs2 += __shfl_xor(cs2, 16); cs2 += __shfl_xor(cs2, 32);
      cs3 += __shfl_xor(cs3, 16); cs3 += __shfl_xor(cs3, 32);
      float v = (g == 0) ? cs0 : (g == 1) ? cs1 : (g == 2) ? cs2 : cs3;
      atomicAdd(&S[b * 256 + coff + g * 16 + lr], v);
    }
  }
}

// --- context partials (bf16): part[b][s][d][e] = sum_{n in slice s} Et[d,n]*Vt[e,n]
__global__ __launch_bounds__(256) void k_ctx(const bf16* __restrict__ Et,
                                             const bf16* __restrict__ Vt,
                                             bf16* __restrict__ part) {
  __shared__ __align__(16) bf16 As0[8192], Bs0[8192], As1[8192], Bs1[8192];
  int bx = blockIdx.x;
  int swz = (bx & 7) * 64 + (bx >> 3);    // 512/8=64 per XCD
  int tile = swz & 3, dblk = tile >> 1, eblk = tile & 1;
  int s = (swz >> 2) & 7;
  int b = swz >> 5;
  int tid = threadIdx.x;
  int lane = tid & 63, w = tid >> 6;
  int wr = w >> 1, wc = w & 1;
  int g = lane >> 4, lr = lane & 15;

  const bf16* Ab = Et + (((size_t)(b * 256 + dblk * 128)) << 12) + s * 512;
  const bf16* Bb = Vt + (((size_t)(b * 256 + eblk * 128)) << 12) + s * 512;

  f32x4 acc[4][4];
#pragma unroll
  for (int m = 0; m < 4; ++m)
#pragma unroll
    for (int n = 0; n < 4; ++n) acc[m][n] = (f32x4)0.0f;

  stage_swz(Ab, 4096, As0, tid);
  stage_swz(Bb, 4096, Bs0, tid);
  __syncthreads();
#pragma unroll
  for (int kp = 0; kp < 4; ++kp) {
    int kt = kp * 2;
    stage_swz(Ab + (kt + 1) * 64, 4096, As1, tid);
    stage_swz(Bb + (kt + 1) * 64, 4096, Bs1, tid);
    compute_tile_swz(As0, Bs0, acc, wr, wc, lr, g);
    __syncthreads();
    if (kt + 2 < 8) {
      stage_swz(Ab + (kt + 2) * 64, 4096, As0, tid);
      stage_swz(Bb + (kt + 2) * 64, 4096, Bs0, tid);
    }
    compute_tile_swz(As1, Bs1, acc, wr, wc, lr, g);
    if (kt + 2 < 8) __syncthreads();
  }

  bf16* p = part + (size_t)(b * 8 + s) * 65536;
  int dbase = dblk * 128 + wr * 64;
  int ebase = eblk * 128 + wc * 64;
#pragma unroll
  for (int m = 0; m < 4; ++m)
#pragma unroll
    for (int n = 0; n < 4; ++n)
#pragma unroll
      for (int t = 0; t < 4; ++t)
        p[(size_t)(dbase + m * 16 + g * 4 + t) * 256 + ebase + n * 16 + lr] = tob(acc[m][n][t]);
}

// --- Wc^T[b][co][d] = sum_e (sum_s part)/S[d] * Wo[e][co], bf16
// 128 blocks: b(16) x dblk(2) x cblk(4); tile 128d x 64co; waves 2x2 of 64x32.
__global__ __launch_bounds__(256) void k_wc(const bf16* __restrict__ part,
                                            const float* __restrict__ S,
                                            const bf16* __restrict__ WoT,
                                            bf16* __restrict__ WcT) {
  __shared__ __align__(16) bf16 As[128 * LDP];
  __shared__ __align__(16) bf16 Bs[64 * LDP];
  int bx = blockIdx.x;
  int b = bx >> 3, dblk = (bx >> 2) & 1, cblk = bx & 3;
  int tid = threadIdx.x;
  int lane = tid & 63, w = tid >> 6;
  int wr = w >> 1, wc = w & 1;
  int g = lane >> 4, lr = lane & 15;
  const bf16* p0 = part + (size_t)b * 8 * 65536;

  f32x4 acc[4][2];
#pragma unroll
  for (int m = 0; m < 4; ++m)
#pragma unroll
    for (int n = 0; n < 2; ++n) acc[m][n] = (f32x4)0.0f;

  for (int kt = 0; kt < 4; ++kt) {
    int k0 = kt * 64;
    __syncthreads();
    // A: reduce 8 bf16 split-K partials, scale 1/S[d], pack bf16
#pragma unroll
    for (int r = 0; r < 8; ++r) {
      int idx = r * 1024 + tid * 4;
      int row = idx >> 6, col = idx & 63;
      int d = dblk * 128 + row;
      size_t off = (size_t)d * 256 + k0 + col;
      float s0 = 0.f, s1 = 0.f, s2 = 0.f, s3 = 0.f;
#pragma unroll
      for (int sl = 0; sl < 8; ++sl) {
        bf16x4 v = *reinterpret_cast<const bf16x4*>(p0 + (size_t)sl * 65536 + off);
        s0 += (float)v[0]; s1 += (float)v[1]; s2 += (float)v[2]; s3 += (float)v[3];
      }
      float rs = 1.0f / S[b * 256 + d];
      bf16x4 p;
      p[0] = tob(s0 * rs); p[1] = tob(s1 * rs); p[2] = tob(s2 * rs); p[3] = tob(s3 * rs);
      *reinterpret_cast<bf16x4*>(&As[row * LDP + col]) = p;
    }
    // B: WoT rows cblk*64 .. +63
#pragma unroll
    for (int r = 0; r < 2; ++r) {
      int idx = r * 2048 + tid * 8;
      int row = idx >> 6, col = idx & 63;
      bf16x8 v = *reinterpret_cast<const bf16x8*>(WoT + (size_t)(cblk * 64 + row) * 256 + k0 + col);
      *reinterpret_cast<bf16x8*>(&Bs[row * LDP + col]) = v;
    }
    __syncthreads();
    compute_tileP2(As, Bs, acc, wr, wc, lr, g);
  }

  int dbase = dblk * 128 + wr * 64;
  int cbase = cblk * 64 + wc * 32;
#pragma unroll
  for (int m = 0; m < 4; ++m)
#pragma unroll
    for (int n = 0; n < 2; ++n) {
      int co = cbase + n * 16 + lr;
      int d0 = dbase + m * 16 + g * 4;
      bf16x4 p;
#pragma unroll
      for (int t = 0; t < 4; ++t) p[t] = tob(acc[m][n][t]);
      *reinterpret_cast<bf16x4*>(&WcT[(size_t)b * 65536 + (size_t)co * 256 + d0]) = p;
    }
}

// --- y[n,co] = Q[n,:] @ Wc + b_out
__global__ __launch_bounds__(256) void k_out(const bf16* __restrict__ Q,
                                             const bf16* __restrict__ WcT,
                                             const float* __restrict__ b_out,
                                             float* __restrict__ y) {
  __shared__ __align__(16) bf16 As0[8192], Bs0[8192], As1[8192], Bs1[8192];
  int bx = blockIdx.x;
  int swz = (bx & 7) * 128 + (bx >> 3);   // 1024/8=128 per XCD
  int rb = swz >> 1, cbk = swz & 1;
  int tid = threadIdx.x;
  int lane = tid & 63, w = tid >> 6;
  int wr = w >> 1, wc = w & 1;
  int g = lane >> 4, lr = lane & 15;
  int rowbase = rb * 128;
  int b = rowbase >> 12;
  const bf16* Ab = Q + (size_t)rowbase * 256;
  const bf16* Bb = WcT + (size_t)b * 65536 + (size_t)(cbk * 128) * 256;

  f32x4 acc[4][4];
#pragma unroll
  for (int m = 0; m < 4; ++m)
#pragma unroll
    for (int n = 0; n < 4; ++n) acc[m][n] = (f32x4)0.0f;

  stage_swz(Ab, 256, As0, tid);
  stage_swz(Bb, 256, Bs0, tid);
  __syncthreads();
#pragma unroll
  for (int kp = 0; kp < 2; ++kp) {
    int kt = kp * 2;
    stage_swz(Ab + (kt + 1) * 64, 256, As1, tid);
    stage_swz(Bb + (kt + 1) * 64, 256, Bs1, tid);
    compute_tile_swz(As0, Bs0, acc, wr, wc, lr, g);
    __syncthreads();
    if (kt + 2 < 4) {
      stage_swz(Ab + (kt + 2) * 64, 256, As0, tid);
      stage_swz(Bb + (kt + 2) * 64, 256, Bs0, tid);
    }
    compute_tile_swz(As1, Bs1, acc, wr, wc, lr, g);
    if (kt + 2 < 4) __syncthreads();
  }

  int cbase = cbk * 128 + wc * 64;
#pragma unroll
  for (int m = 0; m < 4; ++m)
#pragma unroll
    for (int n = 0; n < 4; ++n) {
      int col = cbase + n * 16 + lr;
      float bo = b_out[col];
#pragma unroll
      for (int t = 0; t < 4; ++t) {
        int row = rowbase + wr * 64 + m * 16 + g * 4 + t;
        y[(size_t)row * 256 + col] = acc[m][n][t] + bo;
      }
    }
}

extern "C" void kernel_launch(void* const* d_in, const int* in_sizes, int n_in,
                              void* d_out, int out_size, void* d_ws, size_t ws_size,
                              hipStream_t stream) {
  (void)in_sizes; (void)n_in; (void)out_size; (void)ws_size;
  const float* x  = (const float*)d_in[0];
  const float* Wq = (const float*)d_in[1];
  const float* Wo = (const float*)d_in[2];
  const float* bo = (const float*)d_in[3];
  float* y = (float*)d_out;

  char* ws = (char*)d_ws;
  bf16*  Q    = (bf16*)(ws);                    // 33.55 MB
  bf16*  Et   = (bf16*)(ws + 33554432);         // 33.55 MB
  bf16*  Vt   = (bf16*)(ws + 67108864);         // 33.55 MB
  bf16*  xb   = (bf16*)(ws + 100663296);        // 33.55 MB (dead after k_qkv)
  bf16*  part = (bf16*)(ws + 100663296);        // 16.8 MB bf16, aliases xb
  bf16*  WcT  = (bf16*)(ws + 134217728);        // 2 MB
  bf16*  WqT  = (bf16*)(ws + 136314880);        // 384 KB
  bf16*  WoT  = (bf16*)(ws + 136708096);        // 128 KB
  float* S    = (float*)(ws + 136839168);       // 16 KB

  k_prep<<<dim3(4352), dim3(256), 0, stream>>>(x, Wq, Wo, xb, WqT, WoT, S);
  k_qkv<<<dim3(3072), dim3(256), 0, stream>>>(xb, WqT, Q, Et, Vt, S);
  k_ctx<<<dim3(512), dim3(256), 0, stream>>>(Et, Vt, part);
  k_wc<<<dim3(128), dim3(256), 0, stream>>>(part, S, WoT, WcT);
  k_out<<<dim3(1024), dim3(256), 0, stream>>>(Q, WcT, bo, y);
}